// Round 7
// baseline (1527.390 us; speedup 1.0000x reference)
//
#include <hip/hip_runtime.h>

#define DIM 128
#define NB 782            // ceil(50000/64) dst-buckets of 64 nodes
#define BCAP 1536         // fixed bucket capacity (mean ~1023, +16 sigma)
#define PB_PAD 132        // accumulator row stride: rotates LDS banks per dst row

typedef __attribute__((ext_vector_type(8))) short bf16x8_t;
typedef __attribute__((ext_vector_type(4))) float f32x4_t;

__device__ __forceinline__ short f2bf(float f) {
    unsigned u = __float_as_uint(f);
    u += 0x7FFFu + ((u >> 16) & 1u);        // round-to-nearest-even
    return (short)(u >> 16);
}
__device__ __forceinline__ float bf2f(short s) {
    return __uint_as_float(((unsigned)(unsigned short)s) << 16);
}

// ---------------- Stage 1: bin edges into fixed-cap bucket regions ----------------
// One atomic per bucket per block claims a compact chunk -> stores land in the
// block's own footprint (no cross-XCD partial-line churn).
// binned.x packs (dst&63)<<26 | src  (src < 2^17), binned.y = norm bits.
#define SC_VPT 16
__global__ __launch_bounds__(256) void bucket_scatter(const int* __restrict__ src,
                                                      const int* __restrict__ dst,
                                                      const float* __restrict__ norm,
                                                      int* __restrict__ bcursor,
                                                      int2* __restrict__ binned, int E) {
    __shared__ int hist[NB];
    __shared__ int base[NB];
    int t = threadIdx.x;
    for (int b = t; b < NB; b += 256) hist[b] = 0;
    __syncthreads();

    int e0 = blockIdx.x * (256 * SC_VPT);
    int bkts[SC_VPT];
    int pack[SC_VPT];
    int nrm[SC_VPT];
    #pragma unroll
    for (int k = 0; k < SC_VPT; k++) {
        int e = e0 + k * 256 + t;               // coalesced strided reads
        if (e < E) {
            int d = dst[e];
            bkts[k] = d >> 6;
            pack[k] = ((d & 63) << 26) | src[e];
            nrm[k]  = __float_as_int(norm[e]);
            atomicAdd(&hist[bkts[k]], 1);
        } else bkts[k] = -1;
    }
    __syncthreads();
    for (int b = t; b < NB; b += 256) {
        int c = hist[b];
        base[b] = b * BCAP + (c ? atomicAdd(&bcursor[b], c) : 0);
        hist[b] = 0;
    }
    __syncthreads();
    #pragma unroll
    for (int k = 0; k < SC_VPT; k++) {
        if (bkts[k] >= 0) {
            int pos = base[bkts[k]] + atomicAdd(&hist[bkts[k]], 1);
            binned[pos] = make_int2(pack[k], nrm[k]);
        }
    }
}

// ---------------- GEMM (bf16 MFMA): Cbf[n][128] = bf16( A[n][128] @ W^T )
// W read directly as f32, converted per-fragment (W is L2-hot, 64 KB).
// Block 0 also zeroes ALL NB bucket cursors (strided loop) for the scatter.

__global__ __launch_bounds__(256) void gemm_mfma(const float* __restrict__ A,
                                                 const float* __restrict__ W,
                                                 short* __restrict__ Cbf, int n,
                                                 int* __restrict__ bcursor_zero) {
    if (bcursor_zero != nullptr && blockIdx.x == 0) {
        for (int i = threadIdx.x; i < NB; i += 256) bcursor_zero[i] = 0;
    }

    int wave = threadIdx.x >> 6;
    int lane = threadIdx.x & 63;
    int l16  = lane & 15;
    int quad = lane >> 4;
    int r0 = blockIdx.x * 64 + wave * 16;

    int arow = r0 + l16;
    if (arow >= n) arow = n - 1;               // clamp: OOB rows never stored
    const float* Ar = A + (size_t)arow * DIM + quad * 8;

    bf16x8_t fa[4];
    #pragma unroll
    for (int kk = 0; kk < 4; kk++) {
        float4 x0 = *(const float4*)(Ar + kk * 32);
        float4 x1 = *(const float4*)(Ar + kk * 32 + 4);
        bf16x8_t f;
        f[0] = f2bf(x0.x); f[1] = f2bf(x0.y); f[2] = f2bf(x0.z); f[3] = f2bf(x0.w);
        f[4] = f2bf(x1.x); f[5] = f2bf(x1.y); f[6] = f2bf(x1.z); f[7] = f2bf(x1.w);
        fa[kk] = f;
    }

    #pragma unroll
    for (int ct = 0; ct < 8; ct++) {
        const float* Wr = W + (size_t)(ct * 16 + l16) * DIM + quad * 8;
        f32x4_t acc = {0.f, 0.f, 0.f, 0.f};
        #pragma unroll
        for (int kk = 0; kk < 4; kk++) {
            float4 w0 = *(const float4*)(Wr + kk * 32);
            float4 w1 = *(const float4*)(Wr + kk * 32 + 4);
            bf16x8_t fb;
            fb[0] = f2bf(w0.x); fb[1] = f2bf(w0.y); fb[2] = f2bf(w0.z); fb[3] = f2bf(w0.w);
            fb[4] = f2bf(w1.x); fb[5] = f2bf(w1.y); fb[6] = f2bf(w1.z); fb[7] = f2bf(w1.w);
            acc = __builtin_amdgcn_mfma_f32_16x16x32_bf16(fa[kk], fb, acc, 0, 0, 0);
        }
        #pragma unroll
        for (int j = 0; j < 4; j++) {
            int row = r0 + quad * 4 + j;
            if (row < n) Cbf[(size_t)row * DIM + ct * 16 + l16] = f2bf(acc[j]);
        }
    }
}

// ---------------- Propagate straight from binned buckets ----------------
// One block (512 thr) per 64-node dst-bucket; 64x132 f32 accumulator tile in
// LDS (33.8 KB -> 4 blocks/CU, 32 waves/CU). Quarter-wave (16 lanes) per edge:
// gather the src row (bf16x8/lane), scale, ds_add_f32 into the dst row.
// LDS atomics are fire-and-forget and hide under the gather misses.

__global__ __launch_bounds__(512) void prop_bucket(const short* __restrict__ Sbf,
                                                   const int2* __restrict__ binned,
                                                   const int* __restrict__ bcnt,
                                                   float* __restrict__ out,
                                                   int n, int do_relu) {
    __shared__ float acc[64 * PB_PAD];      // 33792 B
    int b = blockIdx.x;
    int t = threadIdx.x;
    int cnt = bcnt[b];
    for (int i = t; i < 64 * PB_PAD; i += 512) acc[i] = 0.f;
    __syncthreads();

    const int2* eb = binned + (size_t)b * BCAP;
    int q   = t >> 4;                        // 32 quarter-streams per block
    int l16 = t & 15;
    int i = q;
    for (; i + 32 < cnt; i += 64) {          // 2 gathers in flight per stream
        int2 e0 = eb[i];
        int2 e1 = eb[i + 32];
        unsigned p0 = (unsigned)e0.x, p1 = (unsigned)e1.x;
        bf16x8_t v0 = *(const bf16x8_t*)(Sbf + (size_t)(p0 & 0x3FFFFFF) * DIM + l16 * 8);
        bf16x8_t v1 = *(const bf16x8_t*)(Sbf + (size_t)(p1 & 0x3FFFFFF) * DIM + l16 * 8);
        float n0 = __int_as_float(e0.y);
        float n1 = __int_as_float(e1.y);
        float* a0 = &acc[(p0 >> 26) * PB_PAD + l16 * 8];
        float* a1 = &acc[(p1 >> 26) * PB_PAD + l16 * 8];
        #pragma unroll
        for (int j = 0; j < 8; j++) atomicAdd(&a0[j], n0 * bf2f(v0[j]));
        #pragma unroll
        for (int j = 0; j < 8; j++) atomicAdd(&a1[j], n1 * bf2f(v1[j]));
    }
    for (; i < cnt; i += 32) {
        int2 e = eb[i];
        unsigned p = (unsigned)e.x;
        bf16x8_t v = *(const bf16x8_t*)(Sbf + (size_t)(p & 0x3FFFFFF) * DIM + l16 * 8);
        float nv = __int_as_float(e.y);
        float* a = &acc[(p >> 26) * PB_PAD + l16 * 8];
        #pragma unroll
        for (int j = 0; j < 8; j++) atomicAdd(&a[j], nv * bf2f(v[j]));
    }
    __syncthreads();

    // writeback: 64 rows x 32 float4
    int node0 = b << 6;
    for (int k = t; k < 64 * 32; k += 512) {
        int r = k >> 5;
        int c = (k & 31) * 4;
        int node = node0 + r;
        if (node < n) {
            const float* a = &acc[r * PB_PAD + c];
            float4 vv = make_float4(a[0], a[1], a[2], a[3]);
            if (do_relu) {
                vv.x = fmaxf(vv.x, 0.f); vv.y = fmaxf(vv.y, 0.f);
                vv.z = fmaxf(vv.z, 0.f); vv.w = fmaxf(vv.w, 0.f);
            }
            __builtin_nontemporal_store(*(f32x4_t*)&vv,
                                        (f32x4_t*)(out + (size_t)node * DIM + c));
        }
    }
}

// ---------------- launch ----------------

extern "C" void kernel_launch(void* const* d_in, const int* in_sizes, int n_in,
                              void* d_out, int out_size, void* d_ws, size_t ws_size,
                              hipStream_t stream) {
    const float* X    = (const float*)d_in[0];
    const float* W0   = (const float*)d_in[1];
    const float* W1   = (const float*)d_in[2];
    const float* norm = (const float*)d_in[3];
    const int*   src  = (const int*)d_in[4];
    const int*   dst  = (const int*)d_in[5];

    const int N = in_sizes[0] / DIM;   // 50000
    const int E = in_sizes[3];         // 800000

    float* Z = (float*)d_out;
    float* H = (float*)d_out + (size_t)N * DIM;

    // workspace layout (~22.5 MB)
    char* ws = (char*)d_ws;
    short* Sbf    = (short*)ws;                      // 12.8 MB
    size_t off    = (size_t)N * DIM * sizeof(short);
    int*   bcursor= (int*)(ws + off); off += (NB * 4 + 255) / 256 * 256;
    int2*  binned = (int2*)(ws + off); off += (size_t)NB * BCAP * 8;

    const int gemm_grid = (N + 63) / 64;             // 782

    // 1. layer-1 GEMM (also zeroes bucket cursors for the scatter)
    gemm_mfma<<<gemm_grid, 256, 0, stream>>>(X, W0, Sbf, N, bcursor);
    // 2. bucket-sort edges by dst-bucket
    bucket_scatter<<<(E + 256 * SC_VPT - 1) / (256 * SC_VPT), 256, 0, stream>>>(
        src, dst, norm, bcursor, binned, E);
    // 3. layer-1 propagate + relu -> H
    prop_bucket<<<NB, 512, 0, stream>>>(Sbf, binned, bcursor, H, N, 1);
    // 4. layer-2 GEMM
    gemm_mfma<<<gemm_grid, 256, 0, stream>>>(H, W1, Sbf, N, nullptr);
    // 5. layer-2 propagate -> Z
    prop_bucket<<<NB, 512, 0, stream>>>(Sbf, binned, bcursor, Z, N, 0);
}

// Round 8
// 235.427 us; speedup vs baseline: 6.4878x; 6.4878x over previous
//
#include <hip/hip_runtime.h>

#define DIM 128
#define NB 782            // ceil(50000/64) dst-buckets of 64 nodes
#define BCAP 1536         // fixed bucket capacity (mean ~1023, +16 sigma)

typedef __attribute__((ext_vector_type(8))) short bf16x8_t;
typedef __attribute__((ext_vector_type(4))) float f32x4_t;

__device__ __forceinline__ short f2bf(float f) {
    unsigned u = __float_as_uint(f);
    u += 0x7FFFu + ((u >> 16) & 1u);        // round-to-nearest-even
    return (short)(u >> 16);
}
__device__ __forceinline__ float bf2f(short s) {
    return __uint_as_float(((unsigned)(unsigned short)s) << 16);
}

// ---------------- Stage 1: bin edges into fixed-cap bucket regions ----------------
// One atomic per bucket per block claims a compact chunk -> stores land in the
// block's own footprint (no cross-XCD partial-line churn).
// binned.x packs (dst&63)<<26 | src  (src < 2^17), binned.y = norm bits.
#define SC_VPT 16
__global__ __launch_bounds__(256) void bucket_scatter(const int* __restrict__ src,
                                                      const int* __restrict__ dst,
                                                      const float* __restrict__ norm,
                                                      int* __restrict__ bcursor,
                                                      int2* __restrict__ binned, int E) {
    __shared__ int hist[NB];
    __shared__ int base[NB];
    int t = threadIdx.x;
    for (int b = t; b < NB; b += 256) hist[b] = 0;
    __syncthreads();

    int e0 = blockIdx.x * (256 * SC_VPT);
    int bkts[SC_VPT];
    int pack[SC_VPT];
    int nrm[SC_VPT];
    #pragma unroll
    for (int k = 0; k < SC_VPT; k++) {
        int e = e0 + k * 256 + t;               // coalesced strided reads
        if (e < E) {
            int d = dst[e];
            bkts[k] = d >> 6;
            pack[k] = ((d & 63) << 26) | src[e];
            nrm[k]  = __float_as_int(norm[e]);
            atomicAdd(&hist[bkts[k]], 1);
        } else bkts[k] = -1;
    }
    __syncthreads();
    for (int b = t; b < NB; b += 256) {
        int c = hist[b];
        base[b] = b * BCAP + (c ? atomicAdd(&bcursor[b], c) : 0);
        hist[b] = 0;
    }
    __syncthreads();
    #pragma unroll
    for (int k = 0; k < SC_VPT; k++) {
        if (bkts[k] >= 0) {
            int pos = base[bkts[k]] + atomicAdd(&hist[bkts[k]], 1);
            binned[pos] = make_int2(pack[k], nrm[k]);
        }
    }
}

// ---------------- GEMM (bf16 MFMA): Cbf[n][128] = bf16( A[n][128] @ W^T )
// W read directly as f32, converted per-fragment (W is L2-hot, 64 KB).
// Block 0 also zeroes ALL NB bucket cursors (strided loop) for the scatter.

__global__ __launch_bounds__(256) void gemm_mfma(const float* __restrict__ A,
                                                 const float* __restrict__ W,
                                                 short* __restrict__ Cbf, int n,
                                                 int* __restrict__ bcursor_zero) {
    if (bcursor_zero != nullptr && blockIdx.x == 0) {
        for (int i = threadIdx.x; i < NB; i += 256) bcursor_zero[i] = 0;
    }

    int wave = threadIdx.x >> 6;
    int lane = threadIdx.x & 63;
    int l16  = lane & 15;
    int quad = lane >> 4;
    int r0 = blockIdx.x * 64 + wave * 16;

    int arow = r0 + l16;
    if (arow >= n) arow = n - 1;               // clamp: OOB rows never stored
    const float* Ar = A + (size_t)arow * DIM + quad * 8;

    bf16x8_t fa[4];
    #pragma unroll
    for (int kk = 0; kk < 4; kk++) {
        float4 x0 = *(const float4*)(Ar + kk * 32);
        float4 x1 = *(const float4*)(Ar + kk * 32 + 4);
        bf16x8_t f;
        f[0] = f2bf(x0.x); f[1] = f2bf(x0.y); f[2] = f2bf(x0.z); f[3] = f2bf(x0.w);
        f[4] = f2bf(x1.x); f[5] = f2bf(x1.y); f[6] = f2bf(x1.z); f[7] = f2bf(x1.w);
        fa[kk] = f;
    }

    #pragma unroll
    for (int ct = 0; ct < 8; ct++) {
        const float* Wr = W + (size_t)(ct * 16 + l16) * DIM + quad * 8;
        f32x4_t acc = {0.f, 0.f, 0.f, 0.f};
        #pragma unroll
        for (int kk = 0; kk < 4; kk++) {
            float4 w0 = *(const float4*)(Wr + kk * 32);
            float4 w1 = *(const float4*)(Wr + kk * 32 + 4);
            bf16x8_t fb;
            fb[0] = f2bf(w0.x); fb[1] = f2bf(w0.y); fb[2] = f2bf(w0.z); fb[3] = f2bf(w0.w);
            fb[4] = f2bf(w1.x); fb[5] = f2bf(w1.y); fb[6] = f2bf(w1.z); fb[7] = f2bf(w1.w);
            acc = __builtin_amdgcn_mfma_f32_16x16x32_bf16(fa[kk], fb, acc, 0, 0, 0);
        }
        #pragma unroll
        for (int j = 0; j < 4; j++) {
            int row = r0 + quad * 4 + j;
            if (row < n) Cbf[(size_t)row * DIM + ct * 16 + l16] = f2bf(acc[j]);
        }
    }
}

// ---------------- Propagate from binned buckets, in-LDS counting sort -----------
// One block (512 thr) per 64-node bucket. Pass 1: histogram dst&63 (int LDS
// atomics, native). Wave 0 scans 64 bins. Pass 2: scatter edges into a 12 KB
// LDS array sorted by node. Then 8 waves x 8 nodes each: quarter-wave (16
// lanes) register-accumulate gathers (256 B contiguous per edge), shfl_xor
// reduce, one non-temporal row store. No f32 LDS atomics anywhere.

__global__ __launch_bounds__(512) void prop_bucket(const short* __restrict__ Sbf,
                                                   const int2* __restrict__ binned,
                                                   const int* __restrict__ bcnt,
                                                   float* __restrict__ out,
                                                   int n, int do_relu) {
    __shared__ int2 eds[BCAP];          // 12 KB
    __shared__ int  hist[64];           // bin counts -> cursors
    __shared__ int  offs_s[65];
    int b = blockIdx.x;
    int t = threadIdx.x;
    int cnt = bcnt[b];
    if (cnt > BCAP) cnt = BCAP;
    if (t < 64) hist[t] = 0;
    __syncthreads();

    const int2* eb = binned + (size_t)b * BCAP;
    // pass 1: histogram (coalesced global reads, edges land in L2)
    for (int i = t; i < cnt; i += 512)
        atomicAdd(&hist[((unsigned)eb[i].x) >> 26], 1);
    __syncthreads();
    // wave 0: exclusive scan of 64 bins
    if (t < 64) {
        int v = hist[t];
        int s = v;
        #pragma unroll
        for (int o = 1; o < 64; o <<= 1) {
            int x = __shfl_up(s, o, 64);
            if (t >= o) s += x;
        }
        offs_s[t] = s - v;
        if (t == 63) offs_s[64] = s;
        hist[t] = s - v;                // becomes cursor
    }
    __syncthreads();
    // pass 2: scatter into LDS sorted by node
    for (int i = t; i < cnt; i += 512) {
        int2 e = eb[i];
        int pos = atomicAdd(&hist[((unsigned)e.x) >> 26], 1);
        eds[pos] = e;
    }
    __syncthreads();

    // per-node register accumulation
    int wv   = t >> 6;                  // 8 waves
    int lane = t & 63;
    int q    = lane >> 4;
    int l16  = lane & 15;
    int node0 = b << 6;
    for (int nd = wv; nd < 64; nd += 8) {
        int beg = offs_s[nd];
        int end = offs_s[nd + 1];
        float acc[8] = {};
        int i = beg + q;
        for (; i + 4 < end; i += 8) {   // 2 gathers in flight per quarter
            int2 e0 = eds[i];
            int2 e1 = eds[i + 4];
            bf16x8_t v0 = *(const bf16x8_t*)(Sbf + (size_t)((unsigned)e0.x & 0x3FFFFFF) * DIM + l16 * 8);
            bf16x8_t v1 = *(const bf16x8_t*)(Sbf + (size_t)((unsigned)e1.x & 0x3FFFFFF) * DIM + l16 * 8);
            float n0 = __int_as_float(e0.y);
            float n1 = __int_as_float(e1.y);
            #pragma unroll
            for (int j = 0; j < 8; j++) acc[j] += n0 * bf2f(v0[j]);
            #pragma unroll
            for (int j = 0; j < 8; j++) acc[j] += n1 * bf2f(v1[j]);
        }
        for (; i < end; i += 4) {
            int2 e = eds[i];
            bf16x8_t v = *(const bf16x8_t*)(Sbf + (size_t)((unsigned)e.x & 0x3FFFFFF) * DIM + l16 * 8);
            float nv = __int_as_float(e.y);
            #pragma unroll
            for (int j = 0; j < 8; j++) acc[j] += nv * bf2f(v[j]);
        }
        #pragma unroll
        for (int j = 0; j < 8; j++) {
            acc[j] += __shfl_xor(acc[j], 16, 64);
            acc[j] += __shfl_xor(acc[j], 32, 64);
        }
        int node = node0 + nd;
        if (q == 0 && node < n) {
            if (do_relu) {
                #pragma unroll
                for (int j = 0; j < 8; j++) acc[j] = fmaxf(acc[j], 0.f);
            }
            f32x4_t o0 = {acc[0], acc[1], acc[2], acc[3]};
            f32x4_t o1 = {acc[4], acc[5], acc[6], acc[7]};
            float* row = out + (size_t)node * DIM + l16 * 8;
            __builtin_nontemporal_store(o0, (f32x4_t*)row);
            __builtin_nontemporal_store(o1, (f32x4_t*)(row + 4));
        }
    }
}

// ---------------- launch ----------------

extern "C" void kernel_launch(void* const* d_in, const int* in_sizes, int n_in,
                              void* d_out, int out_size, void* d_ws, size_t ws_size,
                              hipStream_t stream) {
    const float* X    = (const float*)d_in[0];
    const float* W0   = (const float*)d_in[1];
    const float* W1   = (const float*)d_in[2];
    const float* norm = (const float*)d_in[3];
    const int*   src  = (const int*)d_in[4];
    const int*   dst  = (const int*)d_in[5];

    const int N = in_sizes[0] / DIM;   // 50000
    const int E = in_sizes[3];         // 800000

    float* Z = (float*)d_out;
    float* H = (float*)d_out + (size_t)N * DIM;

    // workspace layout (~22.5 MB)
    char* ws = (char*)d_ws;
    short* Sbf    = (short*)ws;                      // 12.8 MB
    size_t off    = (size_t)N * DIM * sizeof(short);
    int*   bcursor= (int*)(ws + off); off += (NB * 4 + 255) / 256 * 256;
    int2*  binned = (int2*)(ws + off); off += (size_t)NB * BCAP * 8;

    const int gemm_grid = (N + 63) / 64;             // 782

    // 1. layer-1 GEMM (also zeroes bucket cursors for the scatter)
    gemm_mfma<<<gemm_grid, 256, 0, stream>>>(X, W0, Sbf, N, bcursor);
    // 2. bucket-sort edges by dst-bucket
    bucket_scatter<<<(E + 256 * SC_VPT - 1) / (256 * SC_VPT), 256, 0, stream>>>(
        src, dst, norm, bcursor, binned, E);
    // 3. layer-1 propagate + relu -> H
    prop_bucket<<<NB, 512, 0, stream>>>(Sbf, binned, bcursor, H, N, 1);
    // 4. layer-2 GEMM
    gemm_mfma<<<gemm_grid, 256, 0, stream>>>(H, W1, Sbf, N, nullptr);
    // 5. layer-2 propagate -> Z
    prop_bucket<<<NB, 512, 0, stream>>>(Sbf, binned, bcursor, Z, N, 0);
}

// Round 9
// 227.168 us; speedup vs baseline: 6.7236x; 1.0364x over previous
//
#include <hip/hip_runtime.h>

#define DIM 128
#define NB 782            // ceil(50000/64) dst-buckets of 64 nodes
#define BCAP 1536         // fixed bucket capacity (mean ~1023, +16 sigma)
#define SC_VPT 16         // edges per thread in scatter (4096/block)

typedef __attribute__((ext_vector_type(8))) short bf16x8_t;
typedef __attribute__((ext_vector_type(4))) float f32x4_t;

__device__ __forceinline__ short f2bf(float f) {
    unsigned u = __float_as_uint(f);
    u += 0x7FFFu + ((u >> 16) & 1u);        // round-to-nearest-even
    return (short)(u >> 16);
}
__device__ __forceinline__ float bf2f(short s) {
    return __uint_as_float(((unsigned)(unsigned short)s) << 16);
}

// ---------------- GEMM body (bf16 MFMA): Cbf[n][128] = bf16( A @ W^T ) ---------
// W read as f32, converted per-fragment (L2-hot, 64 KB).
__device__ __forceinline__ void gemm_body(const float* __restrict__ A,
                                          const float* __restrict__ W,
                                          short* __restrict__ Cbf, int n, int blk) {
    int wave = threadIdx.x >> 6;
    int lane = threadIdx.x & 63;
    int l16  = lane & 15;
    int quad = lane >> 4;
    int r0 = blk * 64 + wave * 16;

    int arow = r0 + l16;
    if (arow >= n) arow = n - 1;               // clamp: OOB rows never stored
    const float* Ar = A + (size_t)arow * DIM + quad * 8;

    bf16x8_t fa[4];
    #pragma unroll
    for (int kk = 0; kk < 4; kk++) {
        float4 x0 = *(const float4*)(Ar + kk * 32);
        float4 x1 = *(const float4*)(Ar + kk * 32 + 4);
        bf16x8_t f;
        f[0] = f2bf(x0.x); f[1] = f2bf(x0.y); f[2] = f2bf(x0.z); f[3] = f2bf(x0.w);
        f[4] = f2bf(x1.x); f[5] = f2bf(x1.y); f[6] = f2bf(x1.z); f[7] = f2bf(x1.w);
        fa[kk] = f;
    }

    #pragma unroll
    for (int ct = 0; ct < 8; ct++) {
        const float* Wr = W + (size_t)(ct * 16 + l16) * DIM + quad * 8;
        f32x4_t acc = {0.f, 0.f, 0.f, 0.f};
        #pragma unroll
        for (int kk = 0; kk < 4; kk++) {
            float4 w0 = *(const float4*)(Wr + kk * 32);
            float4 w1 = *(const float4*)(Wr + kk * 32 + 4);
            bf16x8_t fb;
            fb[0] = f2bf(w0.x); fb[1] = f2bf(w0.y); fb[2] = f2bf(w0.z); fb[3] = f2bf(w0.w);
            fb[4] = f2bf(w1.x); fb[5] = f2bf(w1.y); fb[6] = f2bf(w1.z); fb[7] = f2bf(w1.w);
            acc = __builtin_amdgcn_mfma_f32_16x16x32_bf16(fa[kk], fb, acc, 0, 0, 0);
        }
        #pragma unroll
        for (int j = 0; j < 4; j++) {
            int row = r0 + quad * 4 + j;
            if (row < n) Cbf[(size_t)row * DIM + ct * 16 + l16] = f2bf(acc[j]);
        }
    }
}

// ---------------- Scatter body: bin edges into fixed-cap bucket regions --------
// One atomic per bucket per block claims a compact chunk -> stores land in the
// block's own footprint. binned.x packs (dst&63)<<26 | src, binned.y = norm.
__device__ __forceinline__ void scatter_body(const int* __restrict__ src,
                                             const int* __restrict__ dst,
                                             const float* __restrict__ norm,
                                             int* __restrict__ bcursor,
                                             int2* __restrict__ binned, int E, int blk) {
    __shared__ int hist[NB];
    __shared__ int base[NB];
    int t = threadIdx.x;
    for (int b = t; b < NB; b += 256) hist[b] = 0;
    __syncthreads();

    int e0 = blk * (256 * SC_VPT);
    int bkts[SC_VPT];
    int pack[SC_VPT];
    int nrm[SC_VPT];
    #pragma unroll
    for (int k = 0; k < SC_VPT; k++) {
        int e = e0 + k * 256 + t;               // coalesced strided reads
        if (e < E) {
            int d = dst[e];
            bkts[k] = d >> 6;
            pack[k] = ((d & 63) << 26) | src[e];
            nrm[k]  = __float_as_int(norm[e]);
            atomicAdd(&hist[bkts[k]], 1);
        } else bkts[k] = -1;
    }
    __syncthreads();
    for (int b = t; b < NB; b += 256) {
        int c = hist[b];
        base[b] = b * BCAP + (c ? atomicAdd(&bcursor[b], c) : 0);
        hist[b] = 0;
    }
    __syncthreads();
    #pragma unroll
    for (int k = 0; k < SC_VPT; k++) {
        if (bkts[k] >= 0) {
            int pos = base[bkts[k]] + atomicAdd(&hist[bkts[k]], 1);
            binned[pos] = make_int2(pack[k], nrm[k]);
        }
    }
}

// ---------------- Kernel A: gemm1 and scatter fused (independent work) ---------
__global__ __launch_bounds__(256) void fused_gemm_scatter(
        const float* __restrict__ X, const float* __restrict__ W0,
        short* __restrict__ Sbf, int n,
        const int* __restrict__ src, const int* __restrict__ dst,
        const float* __restrict__ norm, int* __restrict__ bcursor,
        int2* __restrict__ binned, int E, int gemmBlocks) {
    if ((int)blockIdx.x < gemmBlocks)
        gemm_body(X, W0, Sbf, n, blockIdx.x);
    else
        scatter_body(src, dst, norm, bcursor, binned, E, blockIdx.x - gemmBlocks);
}

__global__ __launch_bounds__(256) void gemm_mfma(const float* __restrict__ A,
                                                 const float* __restrict__ W,
                                                 short* __restrict__ Cbf, int n) {
    gemm_body(A, W, Cbf, n, blockIdx.x);
}

// ---------------- Propagate from binned buckets -------------------------------
// One block (512 thr) per 64-node bucket.
// mode 0: single-pass load+histogram of the bucket's edges into LDS, 64-bin
//         scan (wave 0), LDS->LDS counting sort, persist sorted edges +
//         per-node offsets to global, then gather phase from LDS.
// mode 1: read persisted offsets, gather phase straight from sorted global
//         edges (broadcast 8B reads per quarter-wave) -- no sorting at all.
// Gather phase: 8 waves x 8 nodes; quarter-wave (16 lanes) register-accumulates
// 256 B contiguous row gathers, shfl_xor reduce, one non-temporal row store.
// No f32 LDS atomics anywhere (gfx950: f32 LDS atomics serialize, R7 post-mortem).

__global__ __launch_bounds__(512) void prop_bucket(const short* __restrict__ Sbf,
                                                   const int2* __restrict__ binned,
                                                   const int* __restrict__ bcnt,
                                                   int2* __restrict__ edges2,
                                                   int* __restrict__ offs_g,
                                                   float* __restrict__ out,
                                                   int n, int do_relu, int mode) {
    __shared__ int2 raw[BCAP];          // 12 KB
    __shared__ int2 eds[BCAP];          // 12 KB
    __shared__ int  hist[64];
    __shared__ int  offs_s[65];
    int b = blockIdx.x;
    int t = threadIdx.x;

    if (mode == 0) {
        int cnt = bcnt[b];
        if (cnt > BCAP) cnt = BCAP;
        if (t < 64) hist[t] = 0;
        __syncthreads();
        const int2* eb = binned + (size_t)b * BCAP;
        for (int i = t; i < cnt; i += 512) {       // single global read
            int2 e = eb[i];
            raw[i] = e;
            atomicAdd(&hist[((unsigned)e.x) >> 26], 1);
        }
        __syncthreads();
        if (t < 64) {                              // wave 0: exclusive scan
            int v = hist[t];
            int s = v;
            #pragma unroll
            for (int o = 1; o < 64; o <<= 1) {
                int x = __shfl_up(s, o, 64);
                if (t >= o) s += x;
            }
            offs_s[t] = s - v;
            if (t == 63) offs_s[64] = s;
            hist[t] = s - v;                       // becomes cursor
        }
        __syncthreads();
        for (int i = t; i < cnt; i += 512) {       // LDS->LDS counting sort
            int2 e = raw[i];
            int pos = atomicAdd(&hist[((unsigned)e.x) >> 26], 1);
            eds[pos] = e;
        }
        __syncthreads();
        // persist sorted edges + offsets for the mode-1 pass
        int2* e2 = edges2 + (size_t)b * BCAP;
        for (int i = t; i < cnt; i += 512) e2[i] = eds[i];
        if (t < 65) offs_g[b * 65 + t] = offs_s[t];
    } else {
        if (t < 65) offs_s[t] = offs_g[b * 65 + t];
        __syncthreads();
    }

    // ---- gather phase ----
    int wv   = t >> 6;                  // 8 waves
    int lane = t & 63;
    int q    = lane >> 4;
    int l16  = lane & 15;
    int node0 = b << 6;
    const int2* eg = edges2 + (size_t)b * BCAP;   // mode-1 source

    for (int nd = wv; nd < 64; nd += 8) {
        int beg = offs_s[nd];
        int end = offs_s[nd + 1];
        float acc[8] = {};
        int i = beg + q;
        if (mode == 0) {
            for (; i + 4 < end; i += 8) {
                int2 e0 = eds[i];
                int2 e1 = eds[i + 4];
                bf16x8_t v0 = *(const bf16x8_t*)(Sbf + (size_t)((unsigned)e0.x & 0x3FFFFFF) * DIM + l16 * 8);
                bf16x8_t v1 = *(const bf16x8_t*)(Sbf + (size_t)((unsigned)e1.x & 0x3FFFFFF) * DIM + l16 * 8);
                float n0 = __int_as_float(e0.y);
                float n1 = __int_as_float(e1.y);
                #pragma unroll
                for (int j = 0; j < 8; j++) acc[j] += n0 * bf2f(v0[j]);
                #pragma unroll
                for (int j = 0; j < 8; j++) acc[j] += n1 * bf2f(v1[j]);
            }
            for (; i < end; i += 4) {
                int2 e = eds[i];
                bf16x8_t v = *(const bf16x8_t*)(Sbf + (size_t)((unsigned)e.x & 0x3FFFFFF) * DIM + l16 * 8);
                float nv = __int_as_float(e.y);
                #pragma unroll
                for (int j = 0; j < 8; j++) acc[j] += nv * bf2f(v[j]);
            }
        } else {
            for (; i + 4 < end; i += 8) {
                int2 e0 = eg[i];
                int2 e1 = eg[i + 4];
                bf16x8_t v0 = *(const bf16x8_t*)(Sbf + (size_t)((unsigned)e0.x & 0x3FFFFFF) * DIM + l16 * 8);
                bf16x8_t v1 = *(const bf16x8_t*)(Sbf + (size_t)((unsigned)e1.x & 0x3FFFFFF) * DIM + l16 * 8);
                float n0 = __int_as_float(e0.y);
                float n1 = __int_as_float(e1.y);
                #pragma unroll
                for (int j = 0; j < 8; j++) acc[j] += n0 * bf2f(v0[j]);
                #pragma unroll
                for (int j = 0; j < 8; j++) acc[j] += n1 * bf2f(v1[j]);
            }
            for (; i < end; i += 4) {
                int2 e = eg[i];
                bf16x8_t v = *(const bf16x8_t*)(Sbf + (size_t)((unsigned)e.x & 0x3FFFFFF) * DIM + l16 * 8);
                float nv = __int_as_float(e.y);
                #pragma unroll
                for (int j = 0; j < 8; j++) acc[j] += nv * bf2f(v[j]);
            }
        }
        #pragma unroll
        for (int j = 0; j < 8; j++) {
            acc[j] += __shfl_xor(acc[j], 16, 64);
            acc[j] += __shfl_xor(acc[j], 32, 64);
        }
        int node = node0 + nd;
        if (q == 0 && node < n) {
            if (do_relu) {
                #pragma unroll
                for (int j = 0; j < 8; j++) acc[j] = fmaxf(acc[j], 0.f);
            }
            f32x4_t o0 = {acc[0], acc[1], acc[2], acc[3]};
            f32x4_t o1 = {acc[4], acc[5], acc[6], acc[7]};
            float* row = out + (size_t)node * DIM + l16 * 8;
            __builtin_nontemporal_store(o0, (f32x4_t*)row);
            __builtin_nontemporal_store(o1, (f32x4_t*)(row + 4));
        }
    }
}

// ---------------- launch ----------------

extern "C" void kernel_launch(void* const* d_in, const int* in_sizes, int n_in,
                              void* d_out, int out_size, void* d_ws, size_t ws_size,
                              hipStream_t stream) {
    const float* X    = (const float*)d_in[0];
    const float* W0   = (const float*)d_in[1];
    const float* W1   = (const float*)d_in[2];
    const float* norm = (const float*)d_in[3];
    const int*   src  = (const int*)d_in[4];
    const int*   dst  = (const int*)d_in[5];

    const int N = in_sizes[0] / DIM;   // 50000
    const int E = in_sizes[3];         // 800000

    float* Z = (float*)d_out;
    float* H = (float*)d_out + (size_t)N * DIM;

    // workspace layout (~32.5 MB)
    char* ws = (char*)d_ws;
    short* Sbf    = (short*)ws;                      // 12.8 MB
    size_t off    = (size_t)N * DIM * sizeof(short);
    int*   bcursor= (int*)(ws + off); off += (NB * 4 + 255) / 256 * 256;
    int*   offs_g = (int*)(ws + off); off += ((size_t)NB * 65 * 4 + 255) / 256 * 256;
    int2*  binned = (int2*)(ws + off); off += (size_t)NB * BCAP * 8;
    int2*  edges2 = (int2*)(ws + off); off += (size_t)NB * BCAP * 8;

    const int gemmBlocks = (N + 63) / 64;            // 782
    const int scBlocks   = (E + 256 * SC_VPT - 1) / (256 * SC_VPT);  // 196

    // 0. zero bucket cursors (tiny)
    hipMemsetAsync(bcursor, 0, NB * sizeof(int), stream);
    // 1. layer-1 GEMM fused with edge bucket-sort (independent work, one dispatch)
    fused_gemm_scatter<<<gemmBlocks + scBlocks, 256, 0, stream>>>(
        X, W0, Sbf, N, src, dst, norm, bcursor, binned, E, gemmBlocks);
    // 2. layer-1 propagate (sorts buckets in LDS, persists sorted CSR) -> H
    prop_bucket<<<NB, 512, 0, stream>>>(Sbf, binned, bcursor, edges2, offs_g, H, N, 1, 0);
    // 3. layer-2 GEMM
    gemm_mfma<<<gemmBlocks, 256, 0, stream>>>(H, W1, Sbf, N);
    // 4. layer-2 propagate (pre-sorted) -> Z
    prop_bucket<<<NB, 512, 0, stream>>>(Sbf, binned, bcursor, edges2, offs_g, Z, N, 0, 1);
}